// Round 1
// baseline (1604.380 us; speedup 1.0000x reference)
//
#include <hip/hip_runtime.h>
#include <math.h>

#define Bq 16
#define Sq 1024
#define Dq 128
#define Hq 8
#define DHq 16
#define DFFq 512
#define Lq 3
#define NCLS 6
#define NROWS (Bq * Sq)   // 16384

// ---------------------------------------------------------------------------
// Tiled fp32 GEMM: C[M,N] = act(A[M,K] @ W[K,N] + bias[N])
// Tile 128x64, K-chunk 32, 256 threads, 8x4 micro-tile per thread.
// M % 128 == 0, N % 64 == 0, K % 32 == 0 (true for all our shapes).
// ---------------------------------------------------------------------------
#define GM 128
#define GN 64
#define GK 32

__global__ __launch_bounds__(256) void gemm_bias_act(
    const float* __restrict__ A, const float* __restrict__ W,
    const float* __restrict__ bias, float* __restrict__ C,
    int M, int N, int K, int do_relu)
{
    __shared__ float As[GM][GK + 1];   // +1 pad: scalar reads hit distinct banks
    __shared__ float Ws[GK][GN + 4];   // +4 pad keeps 16B alignment for float4

    const int tid  = threadIdx.x;
    const int row0 = blockIdx.x * GM;
    const int col0 = blockIdx.y * GN;
    const int tr   = (tid >> 4) << 3;   // 0..120 step 8
    const int tc   = (tid & 15) << 2;   // 0..60  step 4

    const int ar = tid >> 3;            // 0..31
    const int ac = (tid & 7) << 2;      // 0..28
    const int wr = tid >> 4;            // 0..15
    const int wc = (tid & 15) << 2;     // 0..60

    float acc[8][4];
    #pragma unroll
    for (int i = 0; i < 8; ++i)
        #pragma unroll
        for (int j = 0; j < 4; ++j) acc[i][j] = 0.f;

    for (int k0 = 0; k0 < K; k0 += GK) {
        // global loads for this K-chunk
        const float* Ap = A + (size_t)(row0 + ar) * K + k0 + ac;
        float4 a0 = *(const float4*)(Ap);
        float4 a1 = *(const float4*)(Ap + (size_t)32 * K);
        float4 a2 = *(const float4*)(Ap + (size_t)64 * K);
        float4 a3 = *(const float4*)(Ap + (size_t)96 * K);
        const float* Wp = W + (size_t)(k0 + wr) * N + col0 + wc;
        float4 w0 = *(const float4*)(Wp);
        float4 w1 = *(const float4*)(Wp + (size_t)16 * N);

        __syncthreads();   // previous iteration's LDS reads complete

        // store A tile (scalar stores: LDS rows are 33-float strided)
        As[ar][ac + 0] = a0.x; As[ar][ac + 1] = a0.y; As[ar][ac + 2] = a0.z; As[ar][ac + 3] = a0.w;
        As[ar + 32][ac + 0] = a1.x; As[ar + 32][ac + 1] = a1.y; As[ar + 32][ac + 2] = a1.z; As[ar + 32][ac + 3] = a1.w;
        As[ar + 64][ac + 0] = a2.x; As[ar + 64][ac + 1] = a2.y; As[ar + 64][ac + 2] = a2.z; As[ar + 64][ac + 3] = a2.w;
        As[ar + 96][ac + 0] = a3.x; As[ar + 96][ac + 1] = a3.y; As[ar + 96][ac + 2] = a3.z; As[ar + 96][ac + 3] = a3.w;
        *(float4*)&Ws[wr][wc]      = w0;
        *(float4*)&Ws[wr + 16][wc] = w1;

        __syncthreads();   // LDS tile visible to all

        #pragma unroll
        for (int kk = 0; kk < GK; ++kk) {
            float a[8];
            #pragma unroll
            for (int i = 0; i < 8; ++i) a[i] = As[tr + i][kk];
            float4 wv = *(const float4*)&Ws[kk][tc];
            #pragma unroll
            for (int i = 0; i < 8; ++i) {
                acc[i][0] += a[i] * wv.x;
                acc[i][1] += a[i] * wv.y;
                acc[i][2] += a[i] * wv.z;
                acc[i][3] += a[i] * wv.w;
            }
        }
    }

    float4 bv = *(const float4*)&bias[col0 + tc];
    #pragma unroll
    for (int i = 0; i < 8; ++i) {
        float4 r;
        r.x = acc[i][0] + bv.x;
        r.y = acc[i][1] + bv.y;
        r.z = acc[i][2] + bv.z;
        r.w = acc[i][3] + bv.w;
        if (do_relu) {
            r.x = fmaxf(r.x, 0.f); r.y = fmaxf(r.y, 0.f);
            r.z = fmaxf(r.z, 0.f); r.w = fmaxf(r.w, 0.f);
        }
        *(float4*)&C[(size_t)(row0 + tr + i) * N + col0 + tc] = r;
    }
}

// ---------------------------------------------------------------------------
// Flash-style attention, fp32, one thread = one query row, online softmax.
// q,k,v laid out [B,S,D] with head h occupying columns h*16..h*16+15.
// grid.x = B*H*4 (4 chunks of 256 query rows), block = 256.
// ---------------------------------------------------------------------------
__global__ __launch_bounds__(256) void attn_kernel(
    const float* __restrict__ q, const float* __restrict__ k,
    const float* __restrict__ v, float* __restrict__ o)
{
    const int bh = blockIdx.x >> 2;          // 0..B*H-1
    const int rc = blockIdx.x & 3;           // query chunk
    const int b  = bh / Hq;
    const int h  = bh % Hq;
    const int r  = rc * 256 + threadIdx.x;   // query row in [0,S)

    const size_t rowoff = ((size_t)(b * Sq + r)) * Dq + h * DHq;
    const float* qp = q + rowoff;

    float qv[16];
    {
        float4 t0 = *(const float4*)(qp + 0);
        float4 t1 = *(const float4*)(qp + 4);
        float4 t2 = *(const float4*)(qp + 8);
        float4 t3 = *(const float4*)(qp + 12);
        qv[0]=t0.x; qv[1]=t0.y; qv[2]=t0.z; qv[3]=t0.w;
        qv[4]=t1.x; qv[5]=t1.y; qv[6]=t1.z; qv[7]=t1.w;
        qv[8]=t2.x; qv[9]=t2.y; qv[10]=t2.z; qv[11]=t2.w;
        qv[12]=t3.x; qv[13]=t3.y; qv[14]=t3.z; qv[15]=t3.w;
    }

    const float* kbase = k + ((size_t)b * Sq) * Dq + h * DHq;
    const float* vbase = v + ((size_t)b * Sq) * Dq + h * DHq;

    float m = -1e30f, lsum = 0.f;
    float oa[16];
    #pragma unroll
    for (int d = 0; d < 16; ++d) oa[d] = 0.f;

    for (int j = 0; j < Sq; ++j) {
        const float* kr = kbase + (size_t)j * Dq;
        float4 k0 = *(const float4*)(kr + 0);
        float4 k1 = *(const float4*)(kr + 4);
        float4 k2 = *(const float4*)(kr + 8);
        float4 k3 = *(const float4*)(kr + 12);
        float s = qv[0]*k0.x + qv[1]*k0.y + qv[2]*k0.z + qv[3]*k0.w
                + qv[4]*k1.x + qv[5]*k1.y + qv[6]*k1.z + qv[7]*k1.w
                + qv[8]*k2.x + qv[9]*k2.y + qv[10]*k2.z + qv[11]*k2.w
                + qv[12]*k3.x + qv[13]*k3.y + qv[14]*k3.z + qv[15]*k3.w;
        s *= 0.25f;   // 1/sqrt(16)

        float mn   = fmaxf(m, s);
        float corr = __expf(m - mn);   // 0 on first iteration
        float p    = __expf(s - mn);
        lsum = lsum * corr + p;

        const float* vr = vbase + (size_t)j * Dq;
        float4 v0 = *(const float4*)(vr + 0);
        float4 v1 = *(const float4*)(vr + 4);
        float4 v2 = *(const float4*)(vr + 8);
        float4 v3 = *(const float4*)(vr + 12);
        oa[0]  = oa[0]*corr  + p*v0.x;  oa[1]  = oa[1]*corr  + p*v0.y;
        oa[2]  = oa[2]*corr  + p*v0.z;  oa[3]  = oa[3]*corr  + p*v0.w;
        oa[4]  = oa[4]*corr  + p*v1.x;  oa[5]  = oa[5]*corr  + p*v1.y;
        oa[6]  = oa[6]*corr  + p*v1.z;  oa[7]  = oa[7]*corr  + p*v1.w;
        oa[8]  = oa[8]*corr  + p*v2.x;  oa[9]  = oa[9]*corr  + p*v2.y;
        oa[10] = oa[10]*corr + p*v2.z;  oa[11] = oa[11]*corr + p*v2.w;
        oa[12] = oa[12]*corr + p*v3.x;  oa[13] = oa[13]*corr + p*v3.y;
        oa[14] = oa[14]*corr + p*v3.z;  oa[15] = oa[15]*corr + p*v3.w;
        m = mn;
    }

    const float inv = 1.f / lsum;
    float* op = o + rowoff;
    float4 r0, r1, r2, r3;
    r0.x=oa[0]*inv;  r0.y=oa[1]*inv;  r0.z=oa[2]*inv;  r0.w=oa[3]*inv;
    r1.x=oa[4]*inv;  r1.y=oa[5]*inv;  r1.z=oa[6]*inv;  r1.w=oa[7]*inv;
    r2.x=oa[8]*inv;  r2.y=oa[9]*inv;  r2.z=oa[10]*inv; r2.w=oa[11]*inv;
    r3.x=oa[12]*inv; r3.y=oa[13]*inv; r3.z=oa[14]*inv; r3.w=oa[15]*inv;
    *(float4*)(op + 0)  = r0;
    *(float4*)(op + 4)  = r1;
    *(float4*)(op + 8)  = r2;
    *(float4*)(op + 12) = r3;
}

// ---------------------------------------------------------------------------
// out = LayerNorm(a + res) * g + b, rows of 128. One wave per row, 4 rows/block.
// ---------------------------------------------------------------------------
__global__ __launch_bounds__(256) void add_ln_kernel(
    const float* __restrict__ a, const float* __restrict__ res,
    const float* __restrict__ g, const float* __restrict__ bb,
    float* __restrict__ out, float eps)
{
    const int wave = threadIdx.x >> 6;
    const int lane = threadIdx.x & 63;
    const int row  = blockIdx.x * 4 + wave;
    const size_t base = (size_t)row * Dq;

    float v0 = a[base + lane]      + res[base + lane];
    float v1 = a[base + 64 + lane] + res[base + 64 + lane];

    float s = v0 + v1;
    #pragma unroll
    for (int off = 32; off > 0; off >>= 1) s += __shfl_xor(s, off, 64);
    const float mu = s * (1.f / 128.f);

    const float d0 = v0 - mu, d1 = v1 - mu;
    float vs = d0 * d0 + d1 * d1;
    #pragma unroll
    for (int off = 32; off > 0; off >>= 1) vs += __shfl_xor(vs, off, 64);
    const float rstd = rsqrtf(vs * (1.f / 128.f) + eps);

    out[base + lane]      = g[lane]      * d0 * rstd + bb[lane];
    out[base + 64 + lane] = g[lane + 64] * d1 * rstd + bb[lane + 64];
}

// ---------------------------------------------------------------------------
// Final projection: out[row, c] = x[row,:] @ Wout[:, c] + bout[c], c < 6.
// 8 threads per row (2 idle lanes of each 8-group).
// ---------------------------------------------------------------------------
__global__ __launch_bounds__(256) void final_proj_kernel(
    const float* __restrict__ x, const float* __restrict__ Wout,
    const float* __restrict__ bout, float* __restrict__ out)
{
    const int gid = blockIdx.x * 256 + threadIdx.x;
    const int row = gid >> 3;
    const int c   = gid & 7;
    if (row >= NROWS || c >= NCLS) return;
    const float* xr = x + (size_t)row * Dq;
    float acc = bout[c];
    #pragma unroll 16
    for (int kk = 0; kk < Dq; ++kk) acc += xr[kk] * Wout[kk * NCLS + c];
    out[(size_t)row * NCLS + c] = acc;
}

// ---------------------------------------------------------------------------
extern "C" void kernel_launch(void* const* d_in, const int* in_sizes, int n_in,
                              void* d_out, int out_size, void* d_ws, size_t ws_size,
                              hipStream_t stream)
{
    const float* x_in  = (const float*)d_in[0];
    const float* Wq    = (const float*)d_in[1];
    const float* bq    = (const float*)d_in[2];
    const float* Wk    = (const float*)d_in[3];
    const float* bk    = (const float*)d_in[4];
    const float* Wv    = (const float*)d_in[5];
    const float* bv    = (const float*)d_in[6];
    const float* ln1_g = (const float*)d_in[7];
    const float* ln1_b = (const float*)d_in[8];
    const float* W1    = (const float*)d_in[9];
    const float* b1    = (const float*)d_in[10];
    const float* W2    = (const float*)d_in[11];
    const float* b2    = (const float*)d_in[12];
    const float* ln2_g = (const float*)d_in[13];
    const float* ln2_b = (const float*)d_in[14];
    const float* Wout  = (const float*)d_in[15];
    const float* bout  = (const float*)d_in[16];
    float* out = (float*)d_out;

    // workspace layout (floats). h (B*S*DFF = 8M floats) aliases q,k,v,o.
    const size_t NX = (size_t)NROWS * Dq;         // 2M floats
    float* ws   = (float*)d_ws;
    float* qbuf = ws;                 // 2M
    float* kbuf = ws + NX;            // 2M
    float* vbuf = ws + 2 * NX;        // 2M
    float* obuf = ws + 3 * NX;        // 2M
    float* hbuf = ws;                 // 8M, aliases q..o (dead by FFN1 time)
    float* fbuf = ws + 4 * NX;        // 2M
    float* xa   = ws + 5 * NX;        // 2M
    float* xb   = ws + 6 * NX;        // 2M

    const dim3 blk(256);
    const dim3 g_qkv(NROWS / GM, Dq / GN);     // (128, 2)
    const dim3 g_ffn1(NROWS / GM, DFFq / GN);  // (128, 8)
    const dim3 g_ffn2(NROWS / GM, Dq / GN);    // (128, 2)

    const float* xcur = x_in;
    for (int l = 0; l < Lq; ++l) {
        const float* wql = Wq + (size_t)l * Dq * Dq;
        const float* wkl = Wk + (size_t)l * Dq * Dq;
        const float* wvl = Wv + (size_t)l * Dq * Dq;

        gemm_bias_act<<<g_qkv, blk, 0, stream>>>(xcur, wql, bq + l * Dq, qbuf, NROWS, Dq, Dq, 1);
        gemm_bias_act<<<g_qkv, blk, 0, stream>>>(xcur, wkl, bk + l * Dq, kbuf, NROWS, Dq, Dq, 1);
        gemm_bias_act<<<g_qkv, blk, 0, stream>>>(xcur, wvl, bv + l * Dq, vbuf, NROWS, Dq, Dq, 1);

        attn_kernel<<<dim3(Bq * Hq * 4), blk, 0, stream>>>(qbuf, kbuf, vbuf, obuf);

        add_ln_kernel<<<dim3(NROWS / 4), blk, 0, stream>>>(obuf, xcur, ln1_g + l * Dq,
                                                           ln1_b + l * Dq, xa, 1e-8f);

        gemm_bias_act<<<g_ffn1, blk, 0, stream>>>(xa, W1 + (size_t)l * Dq * DFFq,
                                                  b1 + l * DFFq, hbuf, NROWS, DFFq, Dq, 1);
        gemm_bias_act<<<g_ffn2, blk, 0, stream>>>(hbuf, W2 + (size_t)l * DFFq * Dq,
                                                  b2 + l * Dq, fbuf, NROWS, Dq, DFFq, 0);

        add_ln_kernel<<<dim3(NROWS / 4), blk, 0, stream>>>(fbuf, xa, ln2_g + l * Dq,
                                                           ln2_b + l * Dq, xb, 1e-6f);
        xcur = xb;
    }

    final_proj_kernel<<<dim3(NROWS * 8 / 256), blk, 0, stream>>>(xcur, Wout, bout, out);
}